// Round 2
// baseline (175.526 us; speedup 1.0000x reference)
//
#include <hip/hip_runtime.h>
#include <hip/hip_bf16.h>

#define N_BCH 8
#define N_ATM 10000
#define N_ELM 100
#define N_ATOMS_TOT (N_BCH * N_ATM)

typedef int   i4 __attribute__((ext_vector_type(4)));
typedef float f4 __attribute__((ext_vector_type(4)));

__global__ void zero_out_kernel(float* __restrict__ out) {
    if (threadIdx.x < N_BCH) out[threadIdx.x] = 0.0f;
}

// Pre-pass: collapse the elm->(k,radius) dependent gather chain into a single
// float2 table kr[n*N_ATM + atom] = (k[elm], radius[elm]). 640 KB, L2-resident.
__launch_bounds__(256)
__global__ void build_kr_kernel(const int* __restrict__ elm,
                                const float* __restrict__ kparam,
                                const float* __restrict__ radius,
                                float2* __restrict__ kr) {
    int idx = blockIdx.x * blockDim.x + threadIdx.x;
    if (idx < N_ATOMS_TOT) {
        int e = elm[idx];
        kr[idx] = make_float2(kparam[e], radius[e]);
    }
}

__launch_bounds__(256)
__global__ void edge_kernel(const float2* __restrict__ kr,
                            const int* __restrict__ edge_n,
                            const int* __restrict__ edge_i,
                            const int* __restrict__ edge_j,
                            const float* __restrict__ sod,
                            float* __restrict__ out,
                            int nE) {
    float acc[N_BCH];
#pragma unroll
    for (int b = 0; b < N_BCH; ++b) acc[b] = 0.0f;

    const int tid    = blockIdx.x * blockDim.x + threadIdx.x;
    const int stride = gridDim.x * blockDim.x;
    const int nvec   = nE >> 2;

    const i4* en4 = (const i4*)edge_n;
    const i4* ei4 = (const i4*)edge_i;
    const i4* ej4 = (const i4*)edge_j;
    const f4* s4  = (const f4*)sod;

    for (int v = tid; v < nvec; v += stride) {
        i4 nn = __builtin_nontemporal_load(en4 + v);
        i4 ii = __builtin_nontemporal_load(ei4 + v);
        i4 jj = __builtin_nontemporal_load(ej4 + v);
        f4 ss = __builtin_nontemporal_load(s4  + v);

        // Issue all 8 independent gathers up front so they overlap.
        float2 gi[4], gj[4];
#pragma unroll
        for (int u = 0; u < 4; ++u) {
            int base = nn[u] * N_ATM;
            gi[u] = kr[base + ii[u]];
            gj[u] = kr[base + jj[u]];
        }

#pragma unroll
        for (int u = 0; u < 4; ++u) {
            float dis = sqrtf(ss[u]);
            float kk = gi[u].x + gj[u].x;
            float R  = gi[u].y + gj[u].y;
            float d  = dis - R;
            float val = (dis < R) ? kk * d * d : 0.0f;
            int   n  = nn[u];
#pragma unroll
            for (int b = 0; b < N_BCH; ++b)
                acc[b] += (n == b) ? val : 0.0f;
        }
    }

    // scalar tail (nE % 4)
    const int tail_start = nvec << 2;
    const int tail_n = nE - tail_start;
    if (tid < tail_n) {
        int e = tail_start + tid;
        int n = edge_n[e];
        float2 gi = kr[n * N_ATM + edge_i[e]];
        float2 gj = kr[n * N_ATM + edge_j[e]];
        float dis = sqrtf(sod[e]);
        float kk = gi.x + gj.x;
        float R  = gi.y + gj.y;
        float d  = dis - R;
        float val = (dis < R) ? kk * d * d : 0.0f;
#pragma unroll
        for (int b = 0; b < N_BCH; ++b)
            acc[b] += (n == b) ? val : 0.0f;
    }

    // wave(64) shuffle reduction per bin
#pragma unroll
    for (int b = 0; b < N_BCH; ++b) {
        float v = acc[b];
#pragma unroll
        for (int off = 32; off > 0; off >>= 1)
            v += __shfl_down(v, off, 64);
        acc[b] = v;
    }

    __shared__ float smem[4][N_BCH];
    const int wave = threadIdx.x >> 6;
    const int lane = threadIdx.x & 63;
    if (lane == 0) {
#pragma unroll
        for (int b = 0; b < N_BCH; ++b) smem[wave][b] = acc[b];
    }
    __syncthreads();
    if (threadIdx.x < N_BCH) {
        float v = smem[0][threadIdx.x] + smem[1][threadIdx.x] +
                  smem[2][threadIdx.x] + smem[3][threadIdx.x];
        atomicAdd(&out[threadIdx.x], v);
    }
}

extern "C" void kernel_launch(void* const* d_in, const int* in_sizes, int n_in,
                              void* d_out, int out_size, void* d_ws, size_t ws_size,
                              hipStream_t stream) {
    const int*   elm    = (const int*)d_in[0];
    const int*   edge_n = (const int*)d_in[1];
    const int*   edge_i = (const int*)d_in[2];
    const int*   edge_j = (const int*)d_in[3];
    const float* sod    = (const float*)d_in[4];
    const float* kparam = (const float*)d_in[5];
    const float* radius = (const float*)d_in[6];
    float* out = (float*)d_out;
    const int nE = in_sizes[1];

    float2* kr = (float2*)d_ws;  // 640 KB needed; ws is preallocated scratch

    hipLaunchKernelGGL(zero_out_kernel, dim3(1), dim3(64), 0, stream, out);
    hipLaunchKernelGGL(build_kr_kernel, dim3((N_ATOMS_TOT + 255) / 256), dim3(256),
                       0, stream, elm, kparam, radius, kr);
    // 4096 blocks -> 16 blocks/CU queued, 8 resident = 32 waves/CU (100% occ cap)
    hipLaunchKernelGGL(edge_kernel, dim3(4096), dim3(256), 0, stream,
                       kr, edge_n, edge_i, edge_j, sod, out, nE);
}

// Round 3
// 127.880 us; speedup vs baseline: 1.3726x; 1.3726x over previous
//
#include <hip/hip_runtime.h>
#include <hip/hip_bf16.h>

#define N_BCH 8
#define N_ATM 10000
#define N_ELM 100
#define N_ATOMS_TOT (N_BCH * N_ATM)   // 80000

typedef int   i4 __attribute__((ext_vector_type(4)));
typedef float f4 __attribute__((ext_vector_type(4)));

// Pre-pass: pack elm (int32, values <100) into u8 table in ws (80000 B),
// and zero the 8 output accumulators.
__launch_bounds__(256)
__global__ void pack_elm_kernel(const int* __restrict__ elm,
                                unsigned int* __restrict__ elm_u8_as_u32,
                                float* __restrict__ out) {
    int t = blockIdx.x * blockDim.x + threadIdx.x;
    if (t < N_ATOMS_TOT / 4) {
        i4 v = *(const i4*)(elm + 4 * t);
        unsigned int packed = (unsigned int)(v[0] & 0xff)
                            | ((unsigned int)(v[1] & 0xff) << 8)
                            | ((unsigned int)(v[2] & 0xff) << 16)
                            | ((unsigned int)(v[3] & 0xff) << 24);
        elm_u8_as_u32[t] = packed;
    }
    if (blockIdx.x == 0 && threadIdx.x < N_BCH) out[threadIdx.x] = 0.0f;
}

// All divergent accesses go to LDS:
//   s_elm  : 80000 B u8 element types (whole batch)
//   s_kr   : [0..99] = k table, [128..227] = r table (offset 512 B -> ds_read pair)
// LDS total ~81.3 KB -> 2 blocks/CU, 512 thr -> 16 waves/CU.
__launch_bounds__(512, 4)
__global__ void edge_kernel(const unsigned int* __restrict__ elm_u8,
                            const float* __restrict__ kparam,
                            const float* __restrict__ radius,
                            const int* __restrict__ edge_n,
                            const int* __restrict__ edge_i,
                            const int* __restrict__ edge_j,
                            const float* __restrict__ sod,
                            float* __restrict__ out,
                            int nE) {
    __shared__ unsigned int s_elm32[N_ATOMS_TOT / 4];  // 80000 B
    __shared__ float s_kr[256];                        // k @ [0], r @ [128]
    __shared__ float s_red[8][N_BCH];                  // cross-wave reduce

    // ---- stage elm table (int4-vectorized: 5000 x 16B) ----
    {
        const i4* src = (const i4*)elm_u8;
        i4* dst = (i4*)s_elm32;
        for (int t = threadIdx.x; t < N_ATOMS_TOT / 16; t += 512)
            dst[t] = src[t];
        if (threadIdx.x < N_ELM) {
            s_kr[threadIdx.x]       = kparam[threadIdx.x];
            s_kr[128 + threadIdx.x] = radius[threadIdx.x];
        }
    }
    __syncthreads();

    const unsigned char* s_elm = (const unsigned char*)s_elm32;

    float acc[N_BCH];
#pragma unroll
    for (int b = 0; b < N_BCH; ++b) acc[b] = 0.0f;

    const int tid    = blockIdx.x * blockDim.x + threadIdx.x;
    const int stride = gridDim.x * blockDim.x;
    const int nvec   = nE >> 2;

    const i4* en4 = (const i4*)edge_n;
    const i4* ei4 = (const i4*)edge_i;
    const i4* ej4 = (const i4*)edge_j;
    const f4* s4  = (const f4*)sod;

    for (int v = tid; v < nvec; v += stride) {
        i4 nn = __builtin_nontemporal_load(en4 + v);
        i4 ii = __builtin_nontemporal_load(ei4 + v);
        i4 jj = __builtin_nontemporal_load(ej4 + v);
        f4 ss = __builtin_nontemporal_load(s4  + v);

#pragma unroll
        for (int u = 0; u < 4; ++u) {
            int base = nn[u] * N_ATM;
            int ei = s_elm[base + ii[u]];
            int ej = s_elm[base + jj[u]];
            float ki = s_kr[ei], ri = s_kr[128 + ei];
            float kj = s_kr[ej], rj = s_kr[128 + ej];
            float dis = __builtin_amdgcn_sqrtf(ss[u]);
            float kk = ki + kj;
            float R  = ri + rj;
            float d  = dis - R;
            float val = (dis < R) ? kk * d * d : 0.0f;
            int n = nn[u];
#pragma unroll
            for (int b = 0; b < N_BCH; ++b)
                acc[b] += (n == b) ? val : 0.0f;
        }
    }

    // scalar tail (nE % 4) -- handled by global threads in block 0
    const int tail_start = nvec << 2;
    const int tail_n = nE - tail_start;
    if (tid < tail_n) {
        int e = tail_start + tid;
        int n = edge_n[e];
        int ei = s_elm[n * N_ATM + edge_i[e]];
        int ej = s_elm[n * N_ATM + edge_j[e]];
        float dis = __builtin_amdgcn_sqrtf(sod[e]);
        float kk = s_kr[ei] + s_kr[ej];
        float R  = s_kr[128 + ei] + s_kr[128 + ej];
        float d  = dis - R;
        float val = (dis < R) ? kk * d * d : 0.0f;
#pragma unroll
        for (int b = 0; b < N_BCH; ++b)
            acc[b] += (n == b) ? val : 0.0f;
    }

    // wave(64) shuffle reduction per bin
#pragma unroll
    for (int b = 0; b < N_BCH; ++b) {
        float x = acc[b];
#pragma unroll
        for (int off = 32; off > 0; off >>= 1)
            x += __shfl_down(x, off, 64);
        acc[b] = x;
    }

    const int wave = threadIdx.x >> 6;   // 8 waves
    const int lane = threadIdx.x & 63;
    if (lane == 0) {
#pragma unroll
        for (int b = 0; b < N_BCH; ++b) s_red[wave][b] = acc[b];
    }
    __syncthreads();
    if (threadIdx.x < N_BCH) {
        float x = 0.0f;
#pragma unroll
        for (int w = 0; w < 8; ++w) x += s_red[w][threadIdx.x];
        atomicAdd(&out[threadIdx.x], x);
    }
}

extern "C" void kernel_launch(void* const* d_in, const int* in_sizes, int n_in,
                              void* d_out, int out_size, void* d_ws, size_t ws_size,
                              hipStream_t stream) {
    const int*   elm    = (const int*)d_in[0];
    const int*   edge_n = (const int*)d_in[1];
    const int*   edge_i = (const int*)d_in[2];
    const int*   edge_j = (const int*)d_in[3];
    const float* sod    = (const float*)d_in[4];
    const float* kparam = (const float*)d_in[5];
    const float* radius = (const float*)d_in[6];
    float* out = (float*)d_out;
    const int nE = in_sizes[1];

    unsigned int* elm_u8 = (unsigned int*)d_ws;  // 80000 B packed u8 table

    hipLaunchKernelGGL(pack_elm_kernel, dim3((N_ATOMS_TOT / 4 + 255) / 256),
                       dim3(256), 0, stream, elm, elm_u8, out);
    // 512 blocks x 512 thr = 2 blocks/CU (LDS-capped), persistent grid-stride
    hipLaunchKernelGGL(edge_kernel, dim3(512), dim3(512), 0, stream,
                       elm_u8, kparam, radius, edge_n, edge_i, edge_j, sod,
                       out, nE);
}

// Round 4
// 126.150 us; speedup vs baseline: 1.3914x; 1.0137x over previous
//
#include <hip/hip_runtime.h>
#include <hip/hip_bf16.h>
#include <hip/hip_fp16.h>

#define N_BCH 8
#define N_ATM 10000
#define N_ELM 100
#define N_ATOMS_TOT (N_BCH * N_ATM)   // 80000

typedef int   i4 __attribute__((ext_vector_type(4)));
typedef float f4 __attribute__((ext_vector_type(4)));

// Pre-pass: pack elm (int32, values <100) into u8 table in ws (80000 B),
// and zero the 8 output accumulators.
__launch_bounds__(256)
__global__ void pack_elm_kernel(const int* __restrict__ elm,
                                unsigned int* __restrict__ elm_u8_as_u32,
                                float* __restrict__ out) {
    int t = blockIdx.x * blockDim.x + threadIdx.x;
    if (t < N_ATOMS_TOT / 4) {
        i4 v = *(const i4*)(elm + 4 * t);
        unsigned int packed = (unsigned int)(v[0] & 0xff)
                            | ((unsigned int)(v[1] & 0xff) << 8)
                            | ((unsigned int)(v[2] & 0xff) << 16)
                            | ((unsigned int)(v[3] & 0xff) << 24);
        elm_u8_as_u32[t] = packed;
    }
    if (blockIdx.x == 0 && threadIdx.x < N_BCH) out[threadIdx.x] = 0.0f;
}

// All divergent accesses in LDS:
//   s_elm32 : 80000 B u8 element types (whole batch)
//   s_kr    : 100x half2(k,r) -> one ds_read_b32 per endpoint, v_pk_add_f16
// LDS ~81 KB -> 2 blocks/CU x 1024 thr = 32 waves/CU (100% occupancy).
__launch_bounds__(1024, 8)
__global__ void edge_kernel(const unsigned int* __restrict__ elm_u8,
                            const float* __restrict__ kparam,
                            const float* __restrict__ radius,
                            const int* __restrict__ edge_n,
                            const int* __restrict__ edge_i,
                            const int* __restrict__ edge_j,
                            const float* __restrict__ sod,
                            float* __restrict__ out,
                            int nE) {
    __shared__ unsigned int s_elm32[N_ATOMS_TOT / 4];  // 80000 B
    __shared__ __half2 s_kr[128];                      // 512 B (100 used)
    __shared__ float s_red[16][N_BCH];                 // 512 B

    // ---- stage elm table (int4-vectorized: 5000 x 16B) + kr half2 table ----
    {
        const i4* src = (const i4*)elm_u8;
        i4* dst = (i4*)s_elm32;
        for (int t = threadIdx.x; t < N_ATOMS_TOT / 16; t += 1024)
            dst[t] = src[t];
        if (threadIdx.x < N_ELM)
            s_kr[threadIdx.x] =
                __floats2half2_rn(kparam[threadIdx.x], radius[threadIdx.x]);
    }
    __syncthreads();

    const unsigned char* s_elm = (const unsigned char*)s_elm32;

    float acc[N_BCH];
#pragma unroll
    for (int b = 0; b < N_BCH; ++b) acc[b] = 0.0f;

    const int tid    = blockIdx.x * blockDim.x + threadIdx.x;
    const int stride = gridDim.x * blockDim.x;
    const int nvec   = nE >> 2;

    const i4* en4 = (const i4*)edge_n;
    const i4* ei4 = (const i4*)edge_i;
    const i4* ej4 = (const i4*)edge_j;
    const f4* s4  = (const f4*)sod;

    for (int v = tid; v < nvec; v += stride) {
        i4 nn = __builtin_nontemporal_load(en4 + v);
        i4 ii = __builtin_nontemporal_load(ei4 + v);
        i4 jj = __builtin_nontemporal_load(ej4 + v);
        f4 ss = __builtin_nontemporal_load(s4  + v);

#pragma unroll
        for (int u = 0; u < 4; ++u) {
            int n = nn[u];
            int base = n * N_ATM;
            int e_i = s_elm[base + ii[u]];
            int e_j = s_elm[base + jj[u]];
            __half2 krsum = __hadd2(s_kr[e_i], s_kr[e_j]);
            float kk = __low2float(krsum);
            float R  = __high2float(krsum);
            float dis = sqrtf(ss[u]);
            float d  = dis - R;
            float val = (dis < R) ? kk * d * d : 0.0f;
#pragma unroll
            for (int b = 0; b < N_BCH; ++b)
                acc[b] += (n == b) ? val : 0.0f;
        }
    }

    // scalar tail (nE % 4)
    const int tail_start = nvec << 2;
    const int tail_n = nE - tail_start;
    if (tid < tail_n) {
        int e = tail_start + tid;
        int n = edge_n[e];
        int e_i = s_elm[n * N_ATM + edge_i[e]];
        int e_j = s_elm[n * N_ATM + edge_j[e]];
        __half2 krsum = __hadd2(s_kr[e_i], s_kr[e_j]);
        float kk = __low2float(krsum);
        float R  = __high2float(krsum);
        float dis = sqrtf(sod[e]);
        float d  = dis - R;
        float val = (dis < R) ? kk * d * d : 0.0f;
#pragma unroll
        for (int b = 0; b < N_BCH; ++b)
            acc[b] += (n == b) ? val : 0.0f;
    }

    // ---- two-phase wave reduction (27 shuffles instead of 48) ----
    const int lane = threadIdx.x & 63;
    const int wave = threadIdx.x >> 6;   // 16 waves

    // phase 1: butterfly over lane bits 3..5 -> each lane holds the sum of
    // its 8-lane class (lanes sharing lane&7) for all 8 bins
#pragma unroll
    for (int off = 8; off <= 32; off <<= 1) {
#pragma unroll
        for (int b = 0; b < N_BCH; ++b)
            acc[b] += __shfl_xor(acc[b], off, 64);
    }
    // phase 2: lane picks bin j = lane>>3, butterfly over lane bits 0..2
    const int j = lane >> 3;
    float x = acc[0];
#pragma unroll
    for (int b = 1; b < N_BCH; ++b) x = (j == b) ? acc[b] : x;
#pragma unroll
    for (int off = 1; off <= 4; off <<= 1)
        x += __shfl_xor(x, off, 64);

    if ((lane & 7) == 0) s_red[wave][j] = x;
    __syncthreads();
    if (threadIdx.x < N_BCH) {
        float v = 0.0f;
#pragma unroll
        for (int w = 0; w < 16; ++w) v += s_red[w][threadIdx.x];
        atomicAdd(&out[threadIdx.x], v);
    }
}

extern "C" void kernel_launch(void* const* d_in, const int* in_sizes, int n_in,
                              void* d_out, int out_size, void* d_ws, size_t ws_size,
                              hipStream_t stream) {
    const int*   elm    = (const int*)d_in[0];
    const int*   edge_n = (const int*)d_in[1];
    const int*   edge_i = (const int*)d_in[2];
    const int*   edge_j = (const int*)d_in[3];
    const float* sod    = (const float*)d_in[4];
    const float* kparam = (const float*)d_in[5];
    const float* radius = (const float*)d_in[6];
    float* out = (float*)d_out;
    const int nE = in_sizes[1];

    unsigned int* elm_u8 = (unsigned int*)d_ws;  // 80000 B packed u8 table

    hipLaunchKernelGGL(pack_elm_kernel, dim3((N_ATOMS_TOT / 4 + 255) / 256),
                       dim3(256), 0, stream, elm, elm_u8, out);
    // 512 blocks x 1024 thr: 2 blocks/CU resident (LDS-capped), 32 waves/CU
    hipLaunchKernelGGL(edge_kernel, dim3(512), dim3(1024), 0, stream,
                       elm_u8, kparam, radius, edge_n, edge_i, edge_j, sod,
                       out, nE);
}